// Round 2
// baseline (422.860 us; speedup 1.0000x reference)
//
#include <hip/hip_runtime.h>
#include <hip/hip_bf16.h>

#define T_NUM 8192
#define D_DIM 1024
#define O_DIM 1024
#define E_NUM 8
#define CAP   8192
#define BM 128
#define BN 128
#define BK 32

typedef float  f32x4  __attribute__((ext_vector_type(4)));
typedef __bf16 bf16x8 __attribute__((ext_vector_type(8)));

__device__ __forceinline__ void gld_lds16(const void* g, void* l) {
  __builtin_amdgcn_global_load_lds(
      (__attribute__((address_space(1))) void*)(void*)(g),
      (__attribute__((address_space(3))) void*)(l), 16, 0, 0);
}

__device__ __forceinline__ unsigned short f2bf(float f) {
  __hip_bfloat16 h = __float2bfloat16(f);
  return __builtin_bit_cast(unsigned short, h);
}

// ---------------- fp32 -> bf16 conversion (vectorized) ----------------
__global__ __launch_bounds__(256) void cvt_kernel(const float* __restrict__ in,
                                                  ushort* __restrict__ out, int n4) {
  int i = blockIdx.x * 256 + threadIdx.x;
  if (i >= n4) return;
  float4 v = ((const float4*)in)[i];
  ushort4 r;
  r.x = f2bf(v.x); r.y = f2bf(v.y); r.z = f2bf(v.z); r.w = f2bf(v.w);
  ((ushort4*)out)[i] = r;
}

// ---------------- gating: logits, top-2, softmax, scatter ----------------
__global__ __launch_bounds__(256) void gate_kernel(const float* __restrict__ x,
                                                   const float* __restrict__ Wg,
                                                   int* __restrict__ counts,
                                                   int* __restrict__ perm,
                                                   float* __restrict__ wgt) {
  int t    = blockIdx.x * 4 + (threadIdx.x >> 6);
  int lane = threadIdx.x & 63;
  const float4* xv = (const float4*)(x + (long)t * D_DIM);

  float acc[E_NUM];
#pragma unroll
  for (int e = 0; e < E_NUM; ++e) acc[e] = 0.f;

#pragma unroll
  for (int i = 0; i < 4; ++i) {           // 4 float4 per lane -> 1024 floats/wave
    float4 xf = xv[lane + i * 64];
#pragma unroll
    for (int e = 0; e < E_NUM; ++e) {
      const float4* wv = (const float4*)(Wg + e * D_DIM);
      float4 wf = wv[lane + i * 64];
      acc[e] += xf.x * wf.x + xf.y * wf.y + xf.z * wf.z + xf.w * wf.w;
    }
  }

  float logit[E_NUM];
#pragma unroll
  for (int e = 0; e < E_NUM; ++e) {
    float v = acc[e];
    for (int off = 32; off > 0; off >>= 1) v += __shfl_down(v, off);
    logit[e] = v;                          // valid on lane 0
  }

  if (lane == 0) {
    int e0 = 0; float v0 = logit[0];
#pragma unroll
    for (int e = 1; e < E_NUM; ++e)
      if (logit[e] > v0) { v0 = logit[e]; e0 = e; }   // strict > : lowest index wins ties
    int e1 = -1; float v1 = -1e30f;
#pragma unroll
    for (int e = 0; e < E_NUM; ++e) {
      if (e == e0) continue;
      if (logit[e] > v1) { v1 = logit[e]; e1 = e; }
    }
    float ex = expf(v1 - v0);
    float den = 1.f + ex;
    float w0 = 1.f / den;
    float w1 = ex / den;

    int p0 = atomicAdd(&counts[e0], 1);
    perm[e0 * CAP + p0] = t;
    wgt[e0 * CAP + p0] = w0;
    int p1 = atomicAdd(&counts[e1], 1);
    perm[e1 * CAP + p1] = t;
    wgt[e1 * CAP + p1] = w1;
  }
}

// ---------------- grouped expert GEMM (m97 structure) ----------------
// grid = E * 64 * 8 blocks, 256 threads. Block: expert e, row-tile rt, col-tile ct.
__global__ __launch_bounds__(256) void moe_gemm(const __hip_bfloat16* __restrict__ xb,
                                                const __hip_bfloat16* __restrict__ wb,
                                                const float* __restrict__ be,
                                                const int* __restrict__ counts,
                                                const int* __restrict__ perm,
                                                const float* __restrict__ wgt,
                                                float* __restrict__ out) {
  int bid = blockIdx.x;
  int e  = bid >> 9;          // 512 blocks / expert
  int rt = (bid >> 3) & 63;
  int ct = bid & 7;
  int n = counts[e];
  if (rt * BM >= n) return;

  __shared__ __hip_bfloat16 lds_a[BM * BK];   // [128][32] row-major, 8KB
  __shared__ __hip_bfloat16 lds_b[BN * BK];   // [128][32] row-major, 8KB

  int tid  = threadIdx.x;
  int lane = tid & 63;
  int wid  = tid >> 6;
  int wm = wid >> 1, wn = wid & 1;

  // staging geometry: issue j in {0,1}; li = j*256+tid; row = li>>2; colgroup = li&3
  int arow0 = (tid >> 2);        // rows 0..63
  int cg    = tid & 3;
  const int*   permE = perm + e * CAP;
  const float* wgtE  = wgt  + e * CAP;
  int slot0 = min(rt * BM + arow0,      n - 1);
  int slot1 = min(rt * BM + 64 + arow0, n - 1);
  long tok0 = permE[slot0];
  long tok1 = permE[slot1];
  const __hip_bfloat16* ga0 = xb + tok0 * D_DIM + cg * 8;
  const __hip_bfloat16* ga1 = xb + tok1 * D_DIM + cg * 8;
  const __hip_bfloat16* gb0 = wb + ((long)e * O_DIM + ct * BN + arow0) * D_DIM + cg * 8;
  const __hip_bfloat16* gb1 = gb0 + 64 * D_DIM;

  char* lA = (char*)lds_a;
  char* lB = (char*)lds_b;

  f32x4 acc[4][4];
#pragma unroll
  for (int m = 0; m < 4; ++m)
#pragma unroll
    for (int nn = 0; nn < 4; ++nn) acc[m][nn] = (f32x4){0.f, 0.f, 0.f, 0.f};

  int lr = lane & 15;
  int lk = (lane >> 4) * 8;

  for (int k0 = 0; k0 < D_DIM; k0 += BK) {
    __syncthreads();                      // prev compute done before overwrite
    gld_lds16(ga0 + k0, lA +        wid * 1024);
    gld_lds16(ga1 + k0, lA + 4096 + wid * 1024);
    gld_lds16(gb0 + k0, lB +        wid * 1024);
    gld_lds16(gb1 + k0, lB + 4096 + wid * 1024);
    __syncthreads();                      // drains vmcnt -> LDS ready

    bf16x8 af[4], bfr[4];
#pragma unroll
    for (int m = 0; m < 4; ++m)
      af[m] = *(const bf16x8*)(lds_a + (wm * 64 + m * 16 + lr) * BK + lk);
#pragma unroll
    for (int nn = 0; nn < 4; ++nn)
      bfr[nn] = *(const bf16x8*)(lds_b + (wn * 64 + nn * 16 + lr) * BK + lk);

#pragma unroll
    for (int m = 0; m < 4; ++m)
#pragma unroll
      for (int nn = 0; nn < 4; ++nn)
        acc[m][nn] = __builtin_amdgcn_mfma_f32_16x16x32_bf16(af[m], bfr[nn], acc[m][nn], 0, 0, 0);
  }

  // epilogue: out[t, o] += w * (acc + be[e, o]) via fp32 atomics
  int base_m = rt * BM + wm * 64;
  int base_n = ct * BN + wn * 64;
  const float* beE = be + e * O_DIM;
#pragma unroll
  for (int m = 0; m < 4; ++m) {
#pragma unroll
    for (int r = 0; r < 4; ++r) {
      int s = base_m + m * 16 + (lane >> 4) * 4 + r;
      if (s < n) {
        long t  = permE[s];
        float w = wgtE[s];
        float* orow = out + t * O_DIM;
#pragma unroll
        for (int nn = 0; nn < 4; ++nn) {
          int o = base_n + nn * 16 + (lane & 15);
          atomicAdd(&orow[o], w * (acc[m][nn][r] + beE[o]));
        }
      }
    }
  }
}

extern "C" void kernel_launch(void* const* d_in, const int* in_sizes, int n_in,
                              void* d_out, int out_size, void* d_ws, size_t ws_size,
                              hipStream_t stream) {
  const float* x  = (const float*)d_in[0];   // [T, D]
  const float* Wg = (const float*)d_in[1];   // [E, D]
  const float* We = (const float*)d_in[2];   // [E, O, D]
  const float* be = (const float*)d_in[3];   // [E, O]
  float* out = (float*)d_out;                // [T, O]

  char* p = (char*)d_ws;
  __hip_bfloat16* xb = (__hip_bfloat16*)p;  p += (size_t)T_NUM * D_DIM * 2;
  __hip_bfloat16* wb = (__hip_bfloat16*)p;  p += (size_t)E_NUM * O_DIM * D_DIM * 2;
  int* counts = (int*)p;                    p += 256;
  int* perm   = (int*)p;                    p += (size_t)E_NUM * CAP * 4;
  float* wgt  = (float*)p;

  hipMemsetAsync(counts, 0, 256, stream);
  hipMemsetAsync(d_out, 0, (size_t)out_size * sizeof(float), stream);

  int n_x = T_NUM * D_DIM;          // 8388608
  int n_w = E_NUM * O_DIM * D_DIM;  // 8388608
  cvt_kernel<<<n_x / 4 / 256, 256, 0, stream>>>(x,  (ushort*)xb, n_x / 4);
  cvt_kernel<<<n_w / 4 / 256, 256, 0, stream>>>(We, (ushort*)wb, n_w / 4);
  gate_kernel<<<T_NUM / 4, 256, 0, stream>>>(x, Wg, counts, perm, wgt);
  moe_gemm<<<E_NUM * 64 * 8, 256, 0, stream>>>(xb, wb, be, counts, perm, wgt, out);
}

// Round 4
// 249.342 us; speedup vs baseline: 1.6959x; 1.6959x over previous
//
#include <hip/hip_runtime.h>
#include <hip/hip_bf16.h>

#define T_NUM 8192
#define D_DIM 1024
#define O_DIM 1024
#define E_NUM 8
#define CAP   8192
#define BM 128
#define BN 128
#define BK 32

typedef float  f32x4  __attribute__((ext_vector_type(4)));
typedef __bf16 bf16x8 __attribute__((ext_vector_type(8)));

__device__ __forceinline__ void gld_lds16(const void* g, void* l) {
  __builtin_amdgcn_global_load_lds(
      (__attribute__((address_space(1))) void*)(void*)(g),
      (__attribute__((address_space(3))) void*)(l), 16, 0, 0);
}

__device__ __forceinline__ unsigned short f2bf(float f) {
  __hip_bfloat16 h = __float2bfloat16(f);
  return __builtin_bit_cast(unsigned short, h);
}

// ---------------- fp32 -> bf16 conversion (for We) ----------------
__global__ __launch_bounds__(256) void cvt_kernel(const float* __restrict__ in,
                                                  ushort* __restrict__ out, int n4) {
  int i = blockIdx.x * 256 + threadIdx.x;
  if (i >= n4) return;
  float4 v = ((const float4*)in)[i];
  ushort4 r;
  r.x = f2bf(v.x); r.y = f2bf(v.y); r.z = f2bf(v.z); r.w = f2bf(v.w);
  ((ushort4*)out)[i] = r;
}

// ---------------- gating: logits, top-2, softmax, hierarchical scatter ----
// 128 blocks x 256 threads. Block handles 64 tokens (4 waves x 16 tokens).
// Also emits xb = bf16(x) since it streams all of x anyway.
__global__ __launch_bounds__(256) void gate_kernel(const float* __restrict__ x,
                                                   const float* __restrict__ Wg,
                                                   ushort* __restrict__ xb,
                                                   int* __restrict__ counts,
                                                   int* __restrict__ perm,
                                                   float* __restrict__ wgt) {
  __shared__ int   s_sel[64][2];
  __shared__ float s_w[64][2];
  __shared__ int   s_hist[E_NUM];
  __shared__ int   s_cursor[E_NUM];

  int tid  = threadIdx.x;
  int lane = tid & 63;
  int wv   = tid >> 6;
  if (tid < E_NUM) s_hist[tid] = 0;

  int t0 = blockIdx.x * 64;

  for (int it = 0; it < 16; ++it) {
    int tl = wv * 16 + it;
    int t  = t0 + tl;
    const float4* xv = (const float4*)(x + (long)t * D_DIM);
    ushort4* xo = (ushort4*)(xb + (long)t * D_DIM);

    float acc[E_NUM];
#pragma unroll
    for (int e = 0; e < E_NUM; ++e) acc[e] = 0.f;

#pragma unroll
    for (int i = 0; i < 4; ++i) {
      float4 xf = xv[lane + i * 64];
      ushort4 r;
      r.x = f2bf(xf.x); r.y = f2bf(xf.y); r.z = f2bf(xf.z); r.w = f2bf(xf.w);
      xo[lane + i * 64] = r;
#pragma unroll
      for (int e = 0; e < E_NUM; ++e) {
        const float4* wv4 = (const float4*)(Wg + e * D_DIM);
        float4 wf = wv4[lane + i * 64];
        acc[e] += xf.x * wf.x + xf.y * wf.y + xf.z * wf.z + xf.w * wf.w;
      }
    }

    float logit[E_NUM];
#pragma unroll
    for (int e = 0; e < E_NUM; ++e) {
      float v = acc[e];
      for (int off = 32; off > 0; off >>= 1) v += __shfl_down(v, off);
      logit[e] = v;                      // valid on lane 0
    }

    if (lane == 0) {
      int e0 = 0; float v0 = logit[0];
#pragma unroll
      for (int e = 1; e < E_NUM; ++e)
        if (logit[e] > v0) { v0 = logit[e]; e0 = e; }  // strict > : lowest idx wins
      int e1 = -1; float v1 = -1e30f;
#pragma unroll
      for (int e = 0; e < E_NUM; ++e) {
        if (e == e0) continue;
        if (logit[e] > v1) { v1 = logit[e]; e1 = e; }
      }
      float ex  = expf(v1 - v0);
      float den = 1.f + ex;
      s_sel[tl][0] = e0; s_w[tl][0] = 1.f / den;
      s_sel[tl][1] = e1; s_w[tl][1] = ex / den;
    }
  }
  __syncthreads();

  // per-block histogram over 128 entries (LDS atomics)
  if (tid < 128) {
    int e = s_sel[tid >> 1][tid & 1];
    atomicAdd(&s_hist[e], 1);
  }
  __syncthreads();

  // one global atomic per expert per block -> block base
  if (tid < E_NUM) s_cursor[tid] = atomicAdd(&counts[tid], s_hist[tid]);
  __syncthreads();

  // place entries via LDS cursors
  if (tid < 128) {
    int tl = tid >> 1, k = tid & 1;
    int e  = s_sel[tl][k];
    int pos = atomicAdd(&s_cursor[e], 1);
    perm[e * CAP + pos] = t0 + tl;
    wgt [e * CAP + pos] = s_w[tl][k];
  }
}

// ---------------- grouped expert GEMM (m97 structure) ----------------
__global__ __launch_bounds__(256) void moe_gemm(const __hip_bfloat16* __restrict__ xb,
                                                const __hip_bfloat16* __restrict__ wb,
                                                const float* __restrict__ be,
                                                const int* __restrict__ counts,
                                                const int* __restrict__ perm,
                                                const float* __restrict__ wgt,
                                                float* __restrict__ out) {
  int bid = blockIdx.x;
  int e  = bid >> 9;          // 512 blocks / expert
  int rt = (bid >> 3) & 63;
  int ct = bid & 7;
  int n = counts[e];
  if (rt * BM >= n) return;

  __shared__ __hip_bfloat16 lds_a[BM * BK];   // [128][32] row-major, 8KB
  __shared__ __hip_bfloat16 lds_b[BN * BK];   // [128][32] row-major, 8KB

  int tid  = threadIdx.x;
  int lane = tid & 63;
  int wid  = tid >> 6;
  int wm = wid >> 1, wn = wid & 1;

  int arow0 = (tid >> 2);        // rows 0..63
  int cg    = tid & 3;
  const int*   permE = perm + e * CAP;
  const float* wgtE  = wgt  + e * CAP;
  int slot0 = min(rt * BM + arow0,      n - 1);
  int slot1 = min(rt * BM + 64 + arow0, n - 1);
  long tok0 = permE[slot0];
  long tok1 = permE[slot1];
  const __hip_bfloat16* ga0 = xb + tok0 * D_DIM + cg * 8;
  const __hip_bfloat16* ga1 = xb + tok1 * D_DIM + cg * 8;
  const __hip_bfloat16* gb0 = wb + ((long)e * O_DIM + ct * BN + arow0) * D_DIM + cg * 8;
  const __hip_bfloat16* gb1 = gb0 + 64 * D_DIM;

  char* lA = (char*)lds_a;
  char* lB = (char*)lds_b;

  f32x4 acc[4][4];
#pragma unroll
  for (int m = 0; m < 4; ++m)
#pragma unroll
    for (int nn = 0; nn < 4; ++nn) acc[m][nn] = (f32x4){0.f, 0.f, 0.f, 0.f};

  int lr = lane & 15;
  int lk = (lane >> 4) * 8;

  for (int k0 = 0; k0 < D_DIM; k0 += BK) {
    __syncthreads();
    gld_lds16(ga0 + k0, lA +        wid * 1024);
    gld_lds16(ga1 + k0, lA + 4096 + wid * 1024);
    gld_lds16(gb0 + k0, lB +        wid * 1024);
    gld_lds16(gb1 + k0, lB + 4096 + wid * 1024);
    __syncthreads();

    bf16x8 af[4], bfr[4];
#pragma unroll
    for (int m = 0; m < 4; ++m)
      af[m] = *(const bf16x8*)(lds_a + (wm * 64 + m * 16 + lr) * BK + lk);
#pragma unroll
    for (int nn = 0; nn < 4; ++nn)
      bfr[nn] = *(const bf16x8*)(lds_b + (wn * 64 + nn * 16 + lr) * BK + lk);

#pragma unroll
    for (int m = 0; m < 4; ++m)
#pragma unroll
      for (int nn = 0; nn < 4; ++nn)
        acc[m][nn] = __builtin_amdgcn_mfma_f32_16x16x32_bf16(af[m], bfr[nn], acc[m][nn], 0, 0, 0);
  }

  int base_m = rt * BM + wm * 64;
  int base_n = ct * BN + wn * 64;
  const float* beE = be + e * O_DIM;
#pragma unroll
  for (int m = 0; m < 4; ++m) {
#pragma unroll
    for (int r = 0; r < 4; ++r) {
      int s = base_m + m * 16 + (lane >> 4) * 4 + r;
      if (s < n) {
        long t  = permE[s];
        float w = wgtE[s];
        float* orow = out + t * O_DIM;
#pragma unroll
        for (int nn = 0; nn < 4; ++nn) {
          int o = base_n + nn * 16 + (lane & 15);
          atomicAdd(&orow[o], w * (acc[m][nn][r] + beE[o]));
        }
      }
    }
  }
}

extern "C" void kernel_launch(void* const* d_in, const int* in_sizes, int n_in,
                              void* d_out, int out_size, void* d_ws, size_t ws_size,
                              hipStream_t stream) {
  const float* x  = (const float*)d_in[0];   // [T, D]
  const float* Wg = (const float*)d_in[1];   // [E, D]
  const float* We = (const float*)d_in[2];   // [E, O, D]
  const float* be = (const float*)d_in[3];   // [E, O]
  float* out = (float*)d_out;                // [T, O]

  char* p = (char*)d_ws;
  __hip_bfloat16* xb = (__hip_bfloat16*)p;  p += (size_t)T_NUM * D_DIM * 2;
  __hip_bfloat16* wb = (__hip_bfloat16*)p;  p += (size_t)E_NUM * O_DIM * D_DIM * 2;
  int* counts = (int*)p;                    p += 256;
  int* perm   = (int*)p;                    p += (size_t)E_NUM * CAP * 4;
  float* wgt  = (float*)p;

  hipMemsetAsync(counts, 0, 256, stream);
  hipMemsetAsync(d_out, 0, (size_t)out_size * sizeof(float), stream);

  int n_w = E_NUM * O_DIM * D_DIM;  // 8388608
  cvt_kernel<<<n_w / 4 / 256, 256, 0, stream>>>(We, (ushort*)wb, n_w / 4);
  gate_kernel<<<T_NUM / 64, 256, 0, stream>>>(x, Wg, (ushort*)xb, counts, perm, wgt);
  moe_gemm<<<E_NUM * 64 * 8, 256, 0, stream>>>(xb, wb, be, counts, perm, wgt, out);
}